// Round 4
// baseline (191.842 us; speedup 1.0000x reference)
//
#include <hip/hip_runtime.h>
#include <hip/hip_bf16.h>
#include <math.h>

// Problem constants
#define NSUB   3
#define CFEAT  1024
#define KDIM   3072          // 3 * 32 * 32
#define MDIM   1568          // 32 * 49
#define BATCH  32
#define AROWS  1664          // 13 * 128 (padded M so staging needs no bounds check)
#define NK     48            // K-steps of 64

// Output layout (flat f32): ranking[32,3] | cam 3x2x[32,7,7] | feats 3x[32,1024,7,7]
#define OUT_CAM   96
#define OUT_FEAT  9504
#define FEAT_PER_BRANCH (BATCH * CFEAT * 49)   // 1605632

// Workspace byte offsets
#define WS_A      0                                   // bf16 [1664][3072]  10.2 MB
#define WS_W      (AROWS * KDIM * 2)                  // bf16 [3][1024][3072] 18.9 MB
#define WS_POOLED (WS_W + NSUB * CFEAT * KDIM * 2)    // f32  [3][32][1024]
#define WS_H      (WS_POOLED + NSUB * BATCH * CFEAT * 4) // f32 [3][32][512]

typedef __attribute__((ext_vector_type(8))) short bf16x8;
typedef __attribute__((ext_vector_type(4))) float f32x4;

__device__ __forceinline__ short b16(float f){
    __hip_bfloat16 h = __float2bfloat16(f);
    return *reinterpret_cast<short*>(&h);
}
__device__ __forceinline__ bf16x8 pack8(float4 a, float4 b){
    bf16x8 r;
    r[0]=b16(a.x); r[1]=b16(a.y); r[2]=b16(a.z); r[3]=b16(a.w);
    r[4]=b16(b.x); r[5]=b16(b.y); r[6]=b16(b.z); r[7]=b16(b.w);
    return r;
}

// global -> LDS direct copy, 16B per lane (dest = wave-uniform base + lane*16)
typedef const __attribute__((address_space(1))) void* gas1_t;
typedef __attribute__((address_space(3))) void* las3_t;
__device__ __forceinline__ void gl_lds16(const short* g, char* l){
    __builtin_amdgcn_global_load_lds((gas1_t)g, (las3_t)l, 16, 0, 0);
}

// ---------------------------------------------------------------------------
// Fused prep: Wb f32->bf16 flat (blocks 0..4607), im2col x -> A bf16 (rest)
// ---------------------------------------------------------------------------
__global__ void prep_fused(const float* __restrict__ x, const float* __restrict__ w,
                           short* __restrict__ A, short* __restrict__ Wo)
{
    int bid = blockIdx.x;
    if (bid < 4608) {
        int idx = bid * 256 + threadIdx.x;             // per 8 elems of Wb
        const float4* s = (const float4*)(w + (size_t)idx * 8);
        *(bf16x8*)(Wo + (size_t)idx * 8) = pack8(s[0], s[1]);
    } else {
        int idx = (bid - 4608) * 256 + threadIdx.x;    // 0 .. 1568*384-1
        int m  = idx / 384, kq = idx % 384;
        int b  = m / 49, p = m % 49, ph = p / 7, pw = p % 7;
        int k0 = kq * 8;
        int ch = k0 >> 10, r = (k0 >> 5) & 31, s = k0 & 31;
        const float* src = x + (((size_t)(b*3 + ch)*224 + ph*32 + r)*224 + pw*32 + s);
        float4 a = *(const float4*)src, c = *(const float4*)(src + 4);
        *(bf16x8*)(A + (size_t)m * KDIM + k0) = pack8(a, c);
    }
}

// ---------------------------------------------------------------------------
// Conv GEMM bf16 MFMA. Block 128x128, 4 waves (2x2), wave tile 64x64.
// A: global_load_lds, double-buffered (16KB x2), XOR-swizzled via source.
// B: DIRECT global->reg (lanes {l,l+16,l+32,l+48} cover one 64B line; panels
//    L2-resident), double-buffered in regs, prefetched one k-step ahead.
// Grid 3*13*8 = 312, XCD-chunked swizzle (312 = 8*39), nt fastest.
// ---------------------------------------------------------------------------
__global__ __launch_bounds__(256, 2) void conv_mfma(
    const short* __restrict__ A, const short* __restrict__ W,
    const float* __restrict__ bb, float* __restrict__ out)
{
    __shared__ __align__(16) char lds[32768];   // A dbuf: 16KB each

    int bid = (int)blockIdx.x;
    bid = (bid & 7) * 39 + (bid >> 3);          // bijective XCD swizzle
    const int i   = bid / 104;
    const int rem = bid % 104;
    const int mt  = rem >> 3, nt = rem & 7;

    const int t = threadIdx.x, wv = t >> 6, l = t & 63;

    // ---- A staging: per wave 4 gl_lds16 (8 rows of 128B each) ----
    const int lr8 = l >> 3, ls8 = l & 7;
    const short* Ag[4]; int Ad[4];
#pragma unroll
    for (int q = 0; q < 4; ++q) {
        int row = wv*32 + q*8 + lr8;
        int gs  = ls8 ^ (row & 7);              // inverse-swizzled global slot
        Ag[q] = A + (size_t)(mt*128 + row) * KDIM + gs*8;
        Ad[q] = (wv*32 + q*8) * 128;
    }

    // ---- compute geometry ----
    const int wr = wv >> 1, wc = wv & 1;
    const int lrow = l & 15, lsl = l >> 4;
    int ard[4][2];
#pragma unroll
    for (int mi = 0; mi < 4; ++mi) {
        int row = wr*64 + mi*16 + lrow;
        ard[mi][0] = row*128 + ((lsl    ) ^ (row & 7))*16;
        ard[mi][1] = row*128 + ((lsl + 4) ^ (row & 7))*16;
    }
    const short* bp[4][2];
#pragma unroll
    for (int ni = 0; ni < 4; ++ni) {
        int row = i*CFEAT + nt*128 + wc*64 + ni*16 + lrow;
#pragma unroll
        for (int kk = 0; kk < 2; ++kk)
            bp[ni][kk] = W + (size_t)row * KDIM + kk*32 + lsl*8;
    }

    f32x4 acc[4][4] = {};
    bf16x8 bg0[4][2], bg1[4][2];

    // prologue: stage A(0) -> buf0, load B(0) -> bg0
#pragma unroll
    for (int q = 0; q < 4; ++q) gl_lds16(Ag[q], lds + Ad[q]);
#pragma unroll
    for (int ni = 0; ni < 4; ++ni)
#pragma unroll
        for (int kk = 0; kk < 2; ++kk)
            bg0[ni][kk] = *(const bf16x8*)(bp[ni][kk]);

    auto compute = [&](const char* base, bf16x8 (&BG)[4][2]) {
        bf16x8 af[4][2];
#pragma unroll
        for (int mi = 0; mi < 4; ++mi) {
            af[mi][0] = *(const bf16x8*)(base + ard[mi][0]);
            af[mi][1] = *(const bf16x8*)(base + ard[mi][1]);
        }
#pragma unroll
        for (int kk = 0; kk < 2; ++kk)
#pragma unroll
            for (int mi = 0; mi < 4; ++mi)
#pragma unroll
                for (int ni = 0; ni < 4; ++ni)
                    acc[mi][ni] = __builtin_amdgcn_mfma_f32_16x16x32_bf16(
                        af[mi][kk], BG[ni][kk], acc[mi][ni], 0, 0, 0);
    };

    for (int kt = 0; kt < NK; kt += 2) {
        // even step: compute buf0/bg0, prefetch (kt+1) -> buf1/bg1
        __syncthreads();
        {
            const int kn = kt + 1;
#pragma unroll
            for (int q = 0; q < 4; ++q) gl_lds16(Ag[q] + kn*64, lds + 16384 + Ad[q]);
#pragma unroll
            for (int ni = 0; ni < 4; ++ni)
#pragma unroll
                for (int kk = 0; kk < 2; ++kk)
                    bg1[ni][kk] = *(const bf16x8*)(bp[ni][kk] + kn*64);
        }
        compute(lds, bg0);
        // odd step: compute buf1/bg1, prefetch (kt+2) -> buf0/bg0
        __syncthreads();
        if (kt + 2 < NK) {
            const int kn = kt + 2;
#pragma unroll
            for (int q = 0; q < 4; ++q) gl_lds16(Ag[q] + kn*64, lds + Ad[q]);
#pragma unroll
            for (int ni = 0; ni < 4; ++ni)
#pragma unroll
                for (int kk = 0; kk < 2; ++kk)
                    bg0[ni][kk] = *(const bf16x8*)(bp[ni][kk] + kn*64);
        }
        compute(lds + 16384, bg1);
    }

    // epilogue: bias + scatter to feats[i][b][c][p]
    float* featb = out + OUT_FEAT + (size_t)i * FEAT_PER_BRANCH;
    float bias[4];
#pragma unroll
    for (int ni = 0; ni < 4; ++ni)
        bias[ni] = bb[i*CFEAT + nt*128 + wc*64 + ni*16 + lrow];
#pragma unroll
    for (int mi = 0; mi < 4; ++mi) {
        int mbase = mt*128 + wr*64 + mi*16 + lsl*4;
#pragma unroll
        for (int r = 0; r < 4; ++r) {
            int m = mbase + r;
            if (m >= MDIM) continue;
            int b = m/49, p = m%49;
#pragma unroll
            for (int ni = 0; ni < 4; ++ni) {
                int n = nt*128 + wc*64 + ni*16 + lrow;
                featb[(size_t)(b*CFEAT + n)*49 + p] = acc[mi][ni][r] + bias[ni];
            }
        }
    }
}

// ---------------------------------------------------------------------------
// Fused CAM + pool: block per (i,b). Phase A: per-c sums -> pooled.
// Phase B: 4 waves split channels for CAM; weights staged in LDS.
// ---------------------------------------------------------------------------
__global__ __launch_bounds__(256) void cam_pool(
    const float* __restrict__ feat, const float* __restrict__ cls_w,
    float* __restrict__ pooled, float* __restrict__ out_cam)
{
    __shared__ float wsh[2048];
    __shared__ float part[2][4][49];
    int i = blockIdx.x >> 5, b = blockIdx.x & 31;
    int t = threadIdx.x;
    const float* f = feat + ((size_t)(i*BATCH + b)) * CFEAT * 49;
    const float* w = cls_w + (size_t)i * 2 * CFEAT;
    for (int k = t; k < 2048; k += 256) wsh[k] = w[k];

    // pooled: thread t handles c = t + 256q (L1 catches the 196B-stride reuse)
    float* pb = pooled + (size_t)(i*BATCH + b) * CFEAT;
#pragma unroll
    for (int q = 0; q < 4; ++q) {
        int c = t + q*256;
        const float* fc = f + (size_t)c*49;
        float s = 0.f;
        for (int k = 0; k < 49; ++k) s += fc[k];
        pb[c] = s * (1.f/49.f);
    }
    __syncthreads();

    int wv = t >> 6, l = t & 63;
    if (l < 49) {
        float a0 = 0.f, a1 = 0.f;
        for (int c = wv*256; c < wv*256 + 256; ++c) {
            float v = f[(size_t)c*49 + l];
            a0 += wsh[c] * v;
            a1 += wsh[1024 + c] * v;
        }
        part[0][wv][l] = a0;
        part[1][wv][l] = a1;
    }
    __syncthreads();
    if (t < 98) {
        int o = t / 49, p = t % 49;
        float s = part[o][0][p] + part[o][1][p] + part[o][2][p] + part[o][3][p];
        out_cam[((size_t)(i*2 + o)) * MDIM + b*49 + p] = fmaxf(s, 0.f);
    }
}

// ---------------------------------------------------------------------------
// MLP layer 1: 48 blocks (3 x 16 j-chunks of 32). pooled staged in LDS.
// ---------------------------------------------------------------------------
__global__ __launch_bounds__(256) void mlp1_kernel(
    const float* __restrict__ pooled, const float* __restrict__ p1w,
    const float* __restrict__ p1b, float* __restrict__ h)
{
    __shared__ float ps[32 * 256];
    int i = blockIdx.x >> 4, jc = blockIdx.x & 15;
    int t = threadIdx.x;
    int j = jc*32 + (t & 31);
    int bg = (t >> 5) * 4;
    float acc[4] = {};
    const float* wrow = p1w + ((size_t)i*512 + j) * CFEAT;
    for (int kc = 0; kc < 4; ++kc) {
        __syncthreads();
#pragma unroll
        for (int q = 0; q < 8; ++q) {
            int f4 = t + q*256;                  // 0..2047 float4s
            int b = f4 >> 6, k4 = (f4 & 63) * 4;
            *(float4*)&ps[b*256 + k4] =
                *(const float4*)&pooled[((size_t)i*32 + b)*CFEAT + kc*256 + k4];
        }
        __syncthreads();
        const float* wk = wrow + kc*256;
        for (int k = 0; k < 256; k += 4) {
            float4 w4 = *(const float4*)(wk + k);
#pragma unroll
            for (int q = 0; q < 4; ++q) {
                const float* pr = &ps[(bg + q)*256 + k];   // wave-uniform: broadcast
                acc[q] += w4.x*pr[0] + w4.y*pr[1] + w4.z*pr[2] + w4.w*pr[3];
            }
        }
    }
    float bias = p1b[i*512 + j];
#pragma unroll
    for (int q = 0; q < 4; ++q)
        h[((size_t)i*32 + bg + q)*512 + j] = fmaxf(acc[q] + bias, 0.f);
}

// ---------------------------------------------------------------------------
// MLP layer 2 + softmax[:,1]: block per branch.
// ---------------------------------------------------------------------------
__global__ void mlp2_kernel(const float* __restrict__ h, const float* __restrict__ p2w,
                            const float* __restrict__ p2b, float* __restrict__ out)
{
    __shared__ float part[256];
    int i = blockIdx.x, t = threadIdx.x;
    int b = t & 31, kc = t >> 5;                 // kc 0..7, 64 k each
    const float* hv = h + ((size_t)i*32 + b)*512 + kc*64;
    const float* w0 = p2w + (size_t)i*1024 + kc*64;
    const float* w1 = w0 + 512;
    float s = 0.f;
    for (int k = 0; k < 64; ++k) s += hv[k] * (w1[k] - w0[k]);
    part[t] = s;
    __syncthreads();
    if (t < 32) {
        float d = 0.f;
#pragma unroll
        for (int q = 0; q < 8; ++q) d += part[q*32 + t];
        d += p2b[i*2 + 1] - p2b[i*2 + 0];
        out[b*NSUB + i] = 1.f / (1.f + expf(-d));
    }
}

// ---------------------------------------------------------------------------
extern "C" void kernel_launch(void* const* d_in, const int* in_sizes, int n_in,
                              void* d_out, int out_size, void* d_ws, size_t ws_size,
                              hipStream_t stream)
{
    const float* x    = (const float*)d_in[0];
    const float* Wb   = (const float*)d_in[1];
    const float* bbp  = (const float*)d_in[2];
    const float* p1w  = (const float*)d_in[3];
    const float* p1b  = (const float*)d_in[4];
    const float* p2w  = (const float*)d_in[5];
    const float* p2b  = (const float*)d_in[6];
    const float* clsw = (const float*)d_in[7];
    float* out = (float*)d_out;

    char* ws = (char*)d_ws;
    short* A_bf   = (short*)(ws + WS_A);
    short* W_bf   = (short*)(ws + WS_W);
    float* pooled = (float*)(ws + WS_POOLED);
    float* hbuf   = (float*)(ws + WS_H);

    prep_fused<<<4608 + 2352, 256, 0, stream>>>(x, Wb, A_bf, W_bf);
    conv_mfma<<<NSUB*13*8, 256, 0, stream>>>(A_bf, W_bf, bbp, out);
    cam_pool<<<NSUB*BATCH, 256, 0, stream>>>(out + OUT_FEAT, clsw, pooled, out + OUT_CAM);
    mlp1_kernel<<<NSUB*16, 256, 0, stream>>>(pooled, p1w, p1b, hbuf);
    mlp2_kernel<<<NSUB, 256, 0, stream>>>(hbuf, p2w, p2b, out);
}

// Round 5
// 162.041 us; speedup vs baseline: 1.1839x; 1.1839x over previous
//
#include <hip/hip_runtime.h>
#include <hip/hip_bf16.h>
#include <math.h>

// Problem constants
#define NSUB   3
#define CFEAT  1024
#define KDIM   3072          // 3 * 32 * 32
#define MDIM   1568          // 32 * 49
#define BATCH  32
#define AROWS  1664          // 13 * 128 (padded M so staging needs no bounds check)
#define NK     48            // K-steps of 64

// Output layout (flat f32): ranking[32,3] | cam 3x2x[32,7,7] | feats 3x[32,1024,7,7]
#define OUT_CAM   96
#define OUT_FEAT  9504
#define FEAT_PER_BRANCH (BATCH * CFEAT * 49)   // 1605632

// Workspace byte offsets
#define WS_A      0                                      // bf16 [1664][3072]  10.2 MB
#define WS_W      (AROWS * KDIM * 2)                     // bf16 [3][1024][3072] 18.9 MB
#define WS_POOLED (WS_W + NSUB * CFEAT * KDIM * 2)       // f32  [3][32][1024]
#define WS_H      (WS_POOLED + NSUB * BATCH * CFEAT * 4) // f32  [3][32][512]
#define WS_CAMP   (WS_H + NSUB * BATCH * 512 * 4)        // f32  [3][32][8][98] partial CAM

typedef __attribute__((ext_vector_type(8))) short bf16x8;
typedef __attribute__((ext_vector_type(4))) float f32x4;

__device__ __forceinline__ short b16(float f){
    __hip_bfloat16 h = __float2bfloat16(f);
    return *reinterpret_cast<short*>(&h);
}
__device__ __forceinline__ bf16x8 pack8(float4 a, float4 b){
    bf16x8 r;
    r[0]=b16(a.x); r[1]=b16(a.y); r[2]=b16(a.z); r[3]=b16(a.w);
    r[4]=b16(b.x); r[5]=b16(b.y); r[6]=b16(b.z); r[7]=b16(b.w);
    return r;
}

// global -> LDS direct copy, 16B per lane (dest = wave-uniform base + lane*16)
typedef const __attribute__((address_space(1))) void* gas1_t;
typedef __attribute__((address_space(3))) void* las3_t;
__device__ __forceinline__ void gl_lds16(const short* g, char* l){
    __builtin_amdgcn_global_load_lds((gas1_t)g, (las3_t)l, 16, 0, 0);
}

// ---------------------------------------------------------------------------
// Fused prep: Wb f32->bf16 flat (blocks 0..4607), im2col x -> A bf16 (rest)
// ---------------------------------------------------------------------------
__global__ void prep_fused(const float* __restrict__ x, const float* __restrict__ w,
                           short* __restrict__ A, short* __restrict__ Wo)
{
    int bid = blockIdx.x;
    if (bid < 4608) {
        int idx = bid * 256 + threadIdx.x;             // per 8 elems of Wb
        const float4* s = (const float4*)(w + (size_t)idx * 8);
        *(bf16x8*)(Wo + (size_t)idx * 8) = pack8(s[0], s[1]);
    } else {
        int idx = (bid - 4608) * 256 + threadIdx.x;    // 0 .. 1568*384-1
        int m  = idx / 384, kq = idx % 384;
        int b  = m / 49, p = m % 49, ph = p / 7, pw = p % 7;
        int k0 = kq * 8;
        int ch = k0 >> 10, r = (k0 >> 5) & 31, s = k0 & 31;
        const float* src = x + (((size_t)(b*3 + ch)*224 + ph*32 + r)*224 + pw*32 + s);
        float4 a = *(const float4*)src, c = *(const float4*)(src + 4);
        *(bf16x8*)(A + (size_t)m * KDIM + k0) = pack8(a, c);
    }
}

// ---------------------------------------------------------------------------
// Conv GEMM bf16 MFMA. Block 128x64 (round-3 grid: 624 blocks, 2.44/CU),
// 4 waves (2x2), wave tile 64x32.
// A: global_load_lds, dbuf 16KB x2, XOR-swizzled via pre-swizzled source.
// B: DIRECT global->reg (round-4 validated path), dbuf in regs, 1-step ahead.
// XCD-chunked bijective swizzle (624 = 8*78), mt fastest (B panel L2-hot).
// ---------------------------------------------------------------------------
__global__ __launch_bounds__(256, 3) void conv_mfma(
    const short* __restrict__ A, const short* __restrict__ W,
    const float* __restrict__ bb, float* __restrict__ out)
{
    __shared__ __align__(16) char lds[32768];   // A dbuf: 16KB each

    int bid = (int)blockIdx.x;
    bid = (bid & 7) * 78 + (bid >> 3);          // bijective XCD swizzle
    const int i   = bid / 208;
    const int rem = bid % 208;
    const int nt  = rem / 13, mt = rem % 13;    // mt fastest

    const int t = threadIdx.x, wv = t >> 6, l = t & 63;

    // ---- A staging: per wave 4 gl_lds16 (8 rows of 128B each) ----
    const int lr8 = l >> 3, ls8 = l & 7;
    const short* Ag[4]; int Ad[4];
#pragma unroll
    for (int q = 0; q < 4; ++q) {
        int row = wv*32 + q*8 + lr8;
        int gs  = ls8 ^ (row & 7);              // inverse-swizzled global slot
        Ag[q] = A + (size_t)(mt*128 + row) * KDIM + gs*8;
        Ad[q] = (wv*32 + q*8) * 128;
    }

    // ---- compute geometry ----
    const int wr = wv >> 1, wc = wv & 1;
    const int lrow = l & 15, lsl = l >> 4;
    int ard[4][2];
#pragma unroll
    for (int mi = 0; mi < 4; ++mi) {
        int row = wr*64 + mi*16 + lrow;
        ard[mi][0] = row*128 + ((lsl    ) ^ (row & 7))*16;
        ard[mi][1] = row*128 + ((lsl + 4) ^ (row & 7))*16;
    }
    const short* bp[2][2];
#pragma unroll
    for (int ni = 0; ni < 2; ++ni) {
        int row = i*CFEAT + nt*64 + wc*32 + ni*16 + lrow;
#pragma unroll
        for (int kk = 0; kk < 2; ++kk)
            bp[ni][kk] = W + (size_t)row * KDIM + kk*32 + lsl*8;
    }

    f32x4 acc[4][2] = {};
    bf16x8 bg0[2][2], bg1[2][2];

    // prologue: stage A(0) -> buf0, load B(0) -> bg0
#pragma unroll
    for (int q = 0; q < 4; ++q) gl_lds16(Ag[q], lds + Ad[q]);
#pragma unroll
    for (int ni = 0; ni < 2; ++ni)
#pragma unroll
        for (int kk = 0; kk < 2; ++kk)
            bg0[ni][kk] = *(const bf16x8*)(bp[ni][kk]);

    auto compute = [&](const char* base, bf16x8 (&BG)[2][2]) {
        bf16x8 af[4][2];
#pragma unroll
        for (int mi = 0; mi < 4; ++mi) {
            af[mi][0] = *(const bf16x8*)(base + ard[mi][0]);
            af[mi][1] = *(const bf16x8*)(base + ard[mi][1]);
        }
#pragma unroll
        for (int kk = 0; kk < 2; ++kk)
#pragma unroll
            for (int mi = 0; mi < 4; ++mi)
#pragma unroll
                for (int ni = 0; ni < 2; ++ni)
                    acc[mi][ni] = __builtin_amdgcn_mfma_f32_16x16x32_bf16(
                        af[mi][kk], BG[ni][kk], acc[mi][ni], 0, 0, 0);
    };

    for (int kt = 0; kt < NK; kt += 2) {
        // even: compute buf0/bg0, prefetch (kt+1) -> buf1/bg1
        __syncthreads();
        {
            const int kn = kt + 1;
#pragma unroll
            for (int q = 0; q < 4; ++q) gl_lds16(Ag[q] + kn*64, lds + 16384 + Ad[q]);
#pragma unroll
            for (int ni = 0; ni < 2; ++ni)
#pragma unroll
                for (int kk = 0; kk < 2; ++kk)
                    bg1[ni][kk] = *(const bf16x8*)(bp[ni][kk] + kn*64);
        }
        compute(lds, bg0);
        // odd: compute buf1/bg1, prefetch (kt+2) -> buf0/bg0
        __syncthreads();
        if (kt + 2 < NK) {
            const int kn = kt + 2;
#pragma unroll
            for (int q = 0; q < 4; ++q) gl_lds16(Ag[q] + kn*64, lds + Ad[q]);
#pragma unroll
            for (int ni = 0; ni < 2; ++ni)
#pragma unroll
                for (int kk = 0; kk < 2; ++kk)
                    bg0[ni][kk] = *(const bf16x8*)(bp[ni][kk] + kn*64);
        }
        compute(lds + 16384, bg1);
    }

    // epilogue: bias + scatter to feats[i][b][c][p]
    float* featb = out + OUT_FEAT + (size_t)i * FEAT_PER_BRANCH;
    float bias[2];
#pragma unroll
    for (int ni = 0; ni < 2; ++ni)
        bias[ni] = bb[i*CFEAT + nt*64 + wc*32 + ni*16 + lrow];
#pragma unroll
    for (int mi = 0; mi < 4; ++mi) {
        int mbase = mt*128 + wr*64 + mi*16 + lsl*4;
#pragma unroll
        for (int r = 0; r < 4; ++r) {
            int m = mbase + r;
            if (m >= MDIM) continue;
            int b = m/49, p = m%49;
#pragma unroll
            for (int ni = 0; ni < 2; ++ni) {
                int n = nt*64 + wc*32 + ni*16 + lrow;
                featb[(size_t)(b*CFEAT + n)*49 + p] = acc[mi][ni][r] + bias[ni];
            }
        }
    }
}

// ---------------------------------------------------------------------------
// Pool + partial CAM: 768 blocks (i, b, 128-channel chunk), 128 threads.
// Stages the chunk in LDS once; pooled written direct (unique), CAM partial
// per chunk to ws (finalized in mlp1's tail blocks). No atomics.
// ---------------------------------------------------------------------------
__global__ __launch_bounds__(128) void cam_pool(
    const float* __restrict__ feat, const float* __restrict__ cls_w,
    float* __restrict__ pooled, float* __restrict__ camp)
{
    __shared__ float fs[128][50];
    int bid = blockIdx.x;                  // (i*32+b)*8 + ch
    int i = bid >> 8, b = (bid >> 3) & 31, ch = bid & 7;
    int t = threadIdx.x;
    int c0 = ch * 128;
    const float* f = feat + ((size_t)(i*BATCH + b) * CFEAT + c0) * 49;

    // cooperative coalesced load of 128x49 floats
    for (int q = 0; q < 49; ++q) {
        int e = q*128 + t;
        fs[e / 49][e % 49] = f[e];
    }
    __syncthreads();

    // pooled partial: thread t owns channel c0+t (write is unique per block)
    {
        float s = 0.f;
#pragma unroll
        for (int k = 0; k < 49; ++k) s += fs[t][k];
        pooled[(size_t)(i*BATCH + b) * CFEAT + c0 + t] = s * (1.f/49.f);
    }

    // CAM partial: 98 threads -> (o,p); sum over this chunk's 128 channels
    if (t < 98) {
        int o = t / 49, p = t % 49;
        const float* w = cls_w + (size_t)i * 2 * CFEAT + o * CFEAT + c0;
        float s = 0.f;
        for (int c = 0; c < 128; ++c) s += w[c] * fs[c][p];
        camp[(size_t)bid * 98 + t] = s;
    }
}

// ---------------------------------------------------------------------------
// MLP layer 1 (blocks 0..47) + CAM finalize (blocks 48..84).
// ---------------------------------------------------------------------------
__global__ __launch_bounds__(256) void mlp1_kernel(
    const float* __restrict__ pooled, const float* __restrict__ p1w,
    const float* __restrict__ p1b, float* __restrict__ h,
    const float* __restrict__ camp, float* __restrict__ out_cam)
{
    if (blockIdx.x >= 48) {                 // CAM finalize: sum 8 chunk partials
        int fid = (blockIdx.x - 48) * 256 + threadIdx.x;
        if (fid < NSUB * 2 * MDIM) {
            int io = fid / MDIM, rem = fid % MDIM;
            int b = rem / 49, p = rem % 49;
            int i = io >> 1, o = io & 1;
            float s = 0.f;
#pragma unroll
            for (int c = 0; c < 8; ++c)
                s += camp[(size_t)(((i*BATCH + b)*8) + c) * 98 + o*49 + p];
            out_cam[fid] = fmaxf(s, 0.f);
        }
        return;
    }
    __shared__ float ps[32 * 256];
    int i = blockIdx.x >> 4, jc = blockIdx.x & 15;
    int t = threadIdx.x;
    int j = jc*32 + (t & 31);
    int bg = (t >> 5) * 4;
    float acc[4] = {};
    const float* wrow = p1w + ((size_t)i*512 + j) * CFEAT;
    for (int kc = 0; kc < 4; ++kc) {
        __syncthreads();
#pragma unroll
        for (int q = 0; q < 8; ++q) {
            int f4 = t + q*256;                  // 0..2047 float4s
            int b = f4 >> 6, k4 = (f4 & 63) * 4;
            *(float4*)&ps[b*256 + k4] =
                *(const float4*)&pooled[((size_t)i*32 + b)*CFEAT + kc*256 + k4];
        }
        __syncthreads();
        const float* wk = wrow + kc*256;
        for (int k = 0; k < 256; k += 4) {
            float4 w4 = *(const float4*)(wk + k);
#pragma unroll
            for (int q = 0; q < 4; ++q) {
                const float* pr = &ps[(bg + q)*256 + k];   // wave-uniform: broadcast
                acc[q] += w4.x*pr[0] + w4.y*pr[1] + w4.z*pr[2] + w4.w*pr[3];
            }
        }
    }
    float bias = p1b[i*512 + j];
#pragma unroll
    for (int q = 0; q < 4; ++q)
        h[((size_t)i*32 + bg + q)*512 + j] = fmaxf(acc[q] + bias, 0.f);
}

// ---------------------------------------------------------------------------
// MLP layer 2 + softmax[:,1]: block per branch.
// ---------------------------------------------------------------------------
__global__ void mlp2_kernel(const float* __restrict__ h, const float* __restrict__ p2w,
                            const float* __restrict__ p2b, float* __restrict__ out)
{
    __shared__ float part[256];
    int i = blockIdx.x, t = threadIdx.x;
    int b = t & 31, kc = t >> 5;                 // kc 0..7, 64 k each
    const float* hv = h + ((size_t)i*32 + b)*512 + kc*64;
    const float* w0 = p2w + (size_t)i*1024 + kc*64;
    const float* w1 = w0 + 512;
    float s = 0.f;
    for (int k = 0; k < 64; ++k) s += hv[k] * (w1[k] - w0[k]);
    part[t] = s;
    __syncthreads();
    if (t < 32) {
        float d = 0.f;
#pragma unroll
        for (int q = 0; q < 8; ++q) d += part[q*32 + t];
        d += p2b[i*2 + 1] - p2b[i*2 + 0];
        out[b*NSUB + i] = 1.f / (1.f + expf(-d));
    }
}

// ---------------------------------------------------------------------------
extern "C" void kernel_launch(void* const* d_in, const int* in_sizes, int n_in,
                              void* d_out, int out_size, void* d_ws, size_t ws_size,
                              hipStream_t stream)
{
    const float* x    = (const float*)d_in[0];
    const float* Wb   = (const float*)d_in[1];
    const float* bbp  = (const float*)d_in[2];
    const float* p1w  = (const float*)d_in[3];
    const float* p1b  = (const float*)d_in[4];
    const float* p2w  = (const float*)d_in[5];
    const float* p2b  = (const float*)d_in[6];
    const float* clsw = (const float*)d_in[7];
    float* out = (float*)d_out;

    char* ws = (char*)d_ws;
    short* A_bf   = (short*)(ws + WS_A);
    short* W_bf   = (short*)(ws + WS_W);
    float* pooled = (float*)(ws + WS_POOLED);
    float* hbuf   = (float*)(ws + WS_H);
    float* camp   = (float*)(ws + WS_CAMP);

    prep_fused<<<4608 + 2352, 256, 0, stream>>>(x, Wb, A_bf, W_bf);
    conv_mfma<<<NSUB*13*16, 256, 0, stream>>>(A_bf, W_bf, bbp, out);
    cam_pool<<<NSUB*BATCH*8, 128, 0, stream>>>(out + OUT_FEAT, clsw, pooled, camp);
    mlp1_kernel<<<48 + 37, 256, 0, stream>>>(pooled, p1w, p1b, hbuf, camp, out + OUT_CAM);
    mlp2_kernel<<<NSUB, 256, 0, stream>>>(hbuf, p2w, p2b, out);
}

// Round 6
// 124.500 us; speedup vs baseline: 1.5409x; 1.3015x over previous
//
#include <hip/hip_runtime.h>
#include <hip/hip_bf16.h>
#include <math.h>

// Problem constants
#define NSUB   3
#define CFEAT  1024
#define KDIM   3072          // 3 * 32 * 32
#define MDIM   1568          // 32 * 49
#define BATCH  32
#define AROWS  1664          // 13 * 128 (padded M so staging needs no bounds check)
#define NK     48            // K-steps of 64

// Output layout (flat f32): ranking[32,3] | cam 3x2x[32,7,7] | feats 3x[32,1024,7,7]
#define OUT_CAM   96
#define OUT_FEAT  9504
#define FEAT_PER_BRANCH (BATCH * CFEAT * 49)   // 1605632

// Workspace byte offsets
#define WS_A      0                                      // bf16 [1664][3072]  10.2 MB
#define WS_W      (AROWS * KDIM * 2)                     // bf16 [3][1024][3072] 18.9 MB
#define WS_POOLED (WS_W + NSUB * CFEAT * KDIM * 2)       // f32  [3][32][1024]
#define WS_H      (WS_POOLED + NSUB * BATCH * CFEAT * 4) // f32  [3][32][512]
#define WS_CAMP   (WS_H + NSUB * BATCH * 512 * 4)        // f32  [3][32][8][98] partial CAM

#define BUFSZ 24576          // one ring buffer: A 16KB + B 8KB

typedef __attribute__((ext_vector_type(8))) short bf16x8;
typedef __attribute__((ext_vector_type(4))) float f32x4;

__device__ __forceinline__ short b16(float f){
    __hip_bfloat16 h = __float2bfloat16(f);
    return *reinterpret_cast<short*>(&h);
}
__device__ __forceinline__ bf16x8 pack8(float4 a, float4 b){
    bf16x8 r;
    r[0]=b16(a.x); r[1]=b16(a.y); r[2]=b16(a.z); r[3]=b16(a.w);
    r[4]=b16(b.x); r[5]=b16(b.y); r[6]=b16(b.z); r[7]=b16(b.w);
    return r;
}

// global -> LDS direct copy, 16B per lane (dest = wave-uniform base + lane*16)
typedef const __attribute__((address_space(1))) void* gas1_t;
typedef __attribute__((address_space(3))) void* las3_t;
__device__ __forceinline__ void gl_lds16(const short* g, char* l){
    __builtin_amdgcn_global_load_lds((gas1_t)g, (las3_t)l, 16, 0, 0);
}

// ---------------------------------------------------------------------------
// Fused prep: Wb f32->bf16 flat (blocks 0..4607), im2col x -> A bf16 (rest)
// ---------------------------------------------------------------------------
__global__ void prep_fused(const float* __restrict__ x, const float* __restrict__ w,
                           short* __restrict__ A, short* __restrict__ Wo)
{
    int bid = blockIdx.x;
    if (bid < 4608) {
        int idx = bid * 256 + threadIdx.x;             // per 8 elems of Wb
        const float4* s = (const float4*)(w + (size_t)idx * 8);
        *(bf16x8*)(Wo + (size_t)idx * 8) = pack8(s[0], s[1]);
    } else {
        int idx = (bid - 4608) * 256 + threadIdx.x;    // 0 .. 1568*384-1
        int m  = idx / 384, kq = idx % 384;
        int b  = m / 49, p = m % 49, ph = p / 7, pw = p % 7;
        int k0 = kq * 8;
        int ch = k0 >> 10, r = (k0 >> 5) & 31, s = k0 & 31;
        const float* src = x + (((size_t)(b*3 + ch)*224 + ph*32 + r)*224 + pw*32 + s);
        float4 a = *(const float4*)src, c = *(const float4*)(src + 4);
        *(bf16x8*)(A + (size_t)m * KDIM + k0) = pack8(a, c);
    }
}

// ---------------------------------------------------------------------------
// Conv GEMM bf16 MFMA. Round-3 structure (128x64 block, 624 blocks, A+B via
// global_load_lds, XOR swizzle via pre-swizzled source) + T3/T4 pipeline:
// ring-of-3 LDS buffers, prefetch distance 2, ONE raw s_barrier per k-step,
// counted s_waitcnt vmcnt(6) instead of the __syncthreads vmcnt(0) drain.
// Hazards: RAW - L(k) retired before every wave's vmcnt(6)+barrier at end of
// step k-1. WAR - step k writes buf[(k+2)%3]==buf[(k-1)%3], whose reads
// completed before each wave's step-(k-1) MFMAs, hence before that barrier.
// ---------------------------------------------------------------------------
__global__ __launch_bounds__(256, 2) void conv_mfma(
    const short* __restrict__ A, const short* __restrict__ W,
    const float* __restrict__ bb, float* __restrict__ out)
{
    __shared__ __align__(16) char lds[3 * BUFSZ];      // 72 KB ring

    int bid = (int)blockIdx.x;
    bid = (bid & 7) * 78 + (bid >> 3);          // bijective XCD swizzle (624=8*78)
    const int i   = bid / 208;
    const int rem = bid % 208;
    const int nt  = rem / 13, mt = rem % 13;    // mt fastest: B panel L2-hot per XCD

    const int t = threadIdx.x, wv = t >> 6, l = t & 63;

    // ---- staging: per wave A: 4 gl_lds16 (8 rows of 128B), B: 2 ----
    const int lr8 = l >> 3, ls8 = l & 7;
    const short* Ag[4]; int Ad[4];
#pragma unroll
    for (int q = 0; q < 4; ++q) {
        int row = wv*32 + q*8 + lr8;
        int gs  = ls8 ^ (row & 7);              // inverse-swizzled global slot
        Ag[q] = A + (size_t)(mt*128 + row) * KDIM + gs*8;
        Ad[q] = (wv*32 + q*8) * 128;
    }
    const short* Bg[2]; int Bd[2];
#pragma unroll
    for (int q = 0; q < 2; ++q) {
        int row = wv*16 + q*8 + lr8;
        int gs  = ls8 ^ (row & 7);
        Bg[q] = W + ((size_t)i*CFEAT + nt*64 + row) * KDIM + gs*8;
        Bd[q] = 16384 + (wv*16 + q*8) * 128;
    }

    // ---- compute geometry ----
    const int wr = wv >> 1, wc = wv & 1;
    const int lrow = l & 15, lsl = l >> 4;
    int ard[4][2];
#pragma unroll
    for (int mi = 0; mi < 4; ++mi) {
        int row = wr*64 + mi*16 + lrow;
        ard[mi][0] = row*128 + ((lsl    ) ^ (row & 7))*16;
        ard[mi][1] = row*128 + ((lsl + 4) ^ (row & 7))*16;
    }
    int brd[2][2];
#pragma unroll
    for (int ni = 0; ni < 2; ++ni) {
        int row = wc*32 + ni*16 + lrow;
        brd[ni][0] = 16384 + row*128 + ((lsl    ) ^ (row & 7))*16;
        brd[ni][1] = 16384 + row*128 + ((lsl + 4) ^ (row & 7))*16;
    }

    f32x4 acc[4][2] = {};

    // ---- prologue: stage tile0 -> buf0, tile1 -> buf1; wait tile0 only ----
#pragma unroll
    for (int q = 0; q < 4; ++q) gl_lds16(Ag[q],      lds + Ad[q]);
#pragma unroll
    for (int q = 0; q < 2; ++q) gl_lds16(Bg[q],      lds + Bd[q]);
#pragma unroll
    for (int q = 0; q < 4; ++q) gl_lds16(Ag[q] + 64, lds + BUFSZ + Ad[q]);
#pragma unroll
    for (int q = 0; q < 2; ++q) gl_lds16(Bg[q] + 64, lds + BUFSZ + Bd[q]);
    asm volatile("s_waitcnt vmcnt(6)" ::: "memory");
    __builtin_amdgcn_sched_barrier(0);
    __builtin_amdgcn_s_barrier();
    __builtin_amdgcn_sched_barrier(0);

    int cr = 0;                                 // ring read index
    for (int kt = 0; kt < NK; ++kt) {
        const char* base = lds + cr * BUFSZ;
        bf16x8 af[4][2], bg[2][2];
#pragma unroll
        for (int mi = 0; mi < 4; ++mi) {
            af[mi][0] = *(const bf16x8*)(base + ard[mi][0]);
            af[mi][1] = *(const bf16x8*)(base + ard[mi][1]);
        }
#pragma unroll
        for (int ni = 0; ni < 2; ++ni) {
            bg[ni][0] = *(const bf16x8*)(base + brd[ni][0]);
            bg[ni][1] = *(const bf16x8*)(base + brd[ni][1]);
        }
        if (kt + 2 < NK) {                      // prefetch distance 2
            int cw = cr + 2; if (cw >= 3) cw -= 3;
            char* wbuf = lds + cw * BUFSZ;
            const int ko = (kt + 2) * 64;
#pragma unroll
            for (int q = 0; q < 4; ++q) gl_lds16(Ag[q] + ko, wbuf + Ad[q]);
#pragma unroll
            for (int q = 0; q < 2; ++q) gl_lds16(Bg[q] + ko, wbuf + Bd[q]);
        }
        asm volatile("s_waitcnt lgkmcnt(0)" ::: "memory");
        __builtin_amdgcn_sched_barrier(0);
        __builtin_amdgcn_s_setprio(1);
#pragma unroll
        for (int kk = 0; kk < 2; ++kk)
#pragma unroll
            for (int mi = 0; mi < 4; ++mi)
#pragma unroll
                for (int ni = 0; ni < 2; ++ni)
                    acc[mi][ni] = __builtin_amdgcn_mfma_f32_16x16x32_bf16(
                        af[mi][kk], bg[ni][kk], acc[mi][ni], 0, 0, 0);
        __builtin_amdgcn_s_setprio(0);
        __builtin_amdgcn_sched_barrier(0);
        if (kt + 2 < NK) { asm volatile("s_waitcnt vmcnt(6)" ::: "memory"); }
        else             { asm volatile("s_waitcnt vmcnt(0)" ::: "memory"); }
        __builtin_amdgcn_sched_barrier(0);
        __builtin_amdgcn_s_barrier();
        __builtin_amdgcn_sched_barrier(0);
        cr = (cr + 1 == 3) ? 0 : cr + 1;
    }

    // epilogue: bias + scatter to feats[i][b][c][p]
    float* featb = out + OUT_FEAT + (size_t)i * FEAT_PER_BRANCH;
    float bias[2];
#pragma unroll
    for (int ni = 0; ni < 2; ++ni)
        bias[ni] = bb[i*CFEAT + nt*64 + wc*32 + ni*16 + lrow];
#pragma unroll
    for (int mi = 0; mi < 4; ++mi) {
        int mbase = mt*128 + wr*64 + mi*16 + lsl*4;
#pragma unroll
        for (int r = 0; r < 4; ++r) {
            int m = mbase + r;
            if (m >= MDIM) continue;
            int b = m/49, p = m%49;
#pragma unroll
            for (int ni = 0; ni < 2; ++ni) {
                int n = nt*64 + wc*32 + ni*16 + lrow;
                featb[(size_t)(b*CFEAT + n)*49 + p] = acc[mi][ni][r] + bias[ni];
            }
        }
    }
}

// ---------------------------------------------------------------------------
// Pool + partial CAM: 768 blocks (i, b, 128-channel chunk), 128 threads.
// ---------------------------------------------------------------------------
__global__ __launch_bounds__(128) void cam_pool(
    const float* __restrict__ feat, const float* __restrict__ cls_w,
    float* __restrict__ pooled, float* __restrict__ camp)
{
    __shared__ float fs[128][50];
    int bid = blockIdx.x;                  // (i*32+b)*8 + ch
    int i = bid >> 8, b = (bid >> 3) & 31, ch = bid & 7;
    int t = threadIdx.x;
    int c0 = ch * 128;
    const float* f = feat + ((size_t)(i*BATCH + b) * CFEAT + c0) * 49;

    for (int q = 0; q < 49; ++q) {
        int e = q*128 + t;
        fs[e / 49][e % 49] = f[e];
    }
    __syncthreads();

    {
        float s = 0.f;
#pragma unroll
        for (int k = 0; k < 49; ++k) s += fs[t][k];
        pooled[(size_t)(i*BATCH + b) * CFEAT + c0 + t] = s * (1.f/49.f);
    }

    if (t < 98) {
        int o = t / 49, p = t % 49;
        const float* w = cls_w + (size_t)i * 2 * CFEAT + o * CFEAT + c0;
        float s = 0.f;
        for (int c = 0; c < 128; ++c) s += w[c] * fs[c][p];
        camp[(size_t)bid * 98 + t] = s;
    }
}

// ---------------------------------------------------------------------------
// MLP layer 1 (blocks 0..47) + CAM finalize (blocks 48..84).
// ---------------------------------------------------------------------------
__global__ __launch_bounds__(256) void mlp1_kernel(
    const float* __restrict__ pooled, const float* __restrict__ p1w,
    const float* __restrict__ p1b, float* __restrict__ h,
    const float* __restrict__ camp, float* __restrict__ out_cam)
{
    if (blockIdx.x >= 48) {                 // CAM finalize: sum 8 chunk partials
        int fid = (blockIdx.x - 48) * 256 + threadIdx.x;
        if (fid < NSUB * 2 * MDIM) {
            int io = fid / MDIM, rem = fid % MDIM;
            int b = rem / 49, p = rem % 49;
            int i = io >> 1, o = io & 1;
            float s = 0.f;
#pragma unroll
            for (int c = 0; c < 8; ++c)
                s += camp[(size_t)(((i*BATCH + b)*8) + c) * 98 + o*49 + p];
            out_cam[fid] = fmaxf(s, 0.f);
        }
        return;
    }
    __shared__ float ps[32 * 256];
    int i = blockIdx.x >> 4, jc = blockIdx.x & 15;
    int t = threadIdx.x;
    int j = jc*32 + (t & 31);
    int bg = (t >> 5) * 4;
    float acc[4] = {};
    const float* wrow = p1w + ((size_t)i*512 + j) * CFEAT;
    for (int kc = 0; kc < 4; ++kc) {
        __syncthreads();
#pragma unroll
        for (int q = 0; q < 8; ++q) {
            int f4 = t + q*256;                  // 0..2047 float4s
            int b = f4 >> 6, k4 = (f4 & 63) * 4;
            *(float4*)&ps[b*256 + k4] =
                *(const float4*)&pooled[((size_t)i*32 + b)*CFEAT + kc*256 + k4];
        }
        __syncthreads();
        const float* wk = wrow + kc*256;
        for (int k = 0; k < 256; k += 4) {
            float4 w4 = *(const float4*)(wk + k);
#pragma unroll
            for (int q = 0; q < 4; ++q) {
                const float* pr = &ps[(bg + q)*256 + k];   // wave-uniform: broadcast
                acc[q] += w4.x*pr[0] + w4.y*pr[1] + w4.z*pr[2] + w4.w*pr[3];
            }
        }
    }
    float bias = p1b[i*512 + j];
#pragma unroll
    for (int q = 0; q < 4; ++q)
        h[((size_t)i*32 + bg + q)*512 + j] = fmaxf(acc[q] + bias, 0.f);
}

// ---------------------------------------------------------------------------
// MLP layer 2 + softmax[:,1]: block per branch.
// ---------------------------------------------------------------------------
__global__ void mlp2_kernel(const float* __restrict__ h, const float* __restrict__ p2w,
                            const float* __restrict__ p2b, float* __restrict__ out)
{
    __shared__ float part[256];
    int i = blockIdx.x, t = threadIdx.x;
    int b = t & 31, kc = t >> 5;                 // kc 0..7, 64 k each
    const float* hv = h + ((size_t)i*32 + b)*512 + kc*64;
    const float* w0 = p2w + (size_t)i*1024 + kc*64;
    const float* w1 = w0 + 512;
    float s = 0.f;
    for (int k = 0; k < 64; ++k) s += hv[k] * (w1[k] - w0[k]);
    part[t] = s;
    __syncthreads();
    if (t < 32) {
        float d = 0.f;
#pragma unroll
        for (int q = 0; q < 8; ++q) d += part[q*32 + t];
        d += p2b[i*2 + 1] - p2b[i*2 + 0];
        out[b*NSUB + i] = 1.f / (1.f + expf(-d));
    }
}

// ---------------------------------------------------------------------------
extern "C" void kernel_launch(void* const* d_in, const int* in_sizes, int n_in,
                              void* d_out, int out_size, void* d_ws, size_t ws_size,
                              hipStream_t stream)
{
    const float* x    = (const float*)d_in[0];
    const float* Wb   = (const float*)d_in[1];
    const float* bbp  = (const float*)d_in[2];
    const float* p1w  = (const float*)d_in[3];
    const float* p1b  = (const float*)d_in[4];
    const float* p2w  = (const float*)d_in[5];
    const float* p2b  = (const float*)d_in[6];
    const float* clsw = (const float*)d_in[7];
    float* out = (float*)d_out;

    char* ws = (char*)d_ws;
    short* A_bf   = (short*)(ws + WS_A);
    short* W_bf   = (short*)(ws + WS_W);
    float* pooled = (float*)(ws + WS_POOLED);
    float* hbuf   = (float*)(ws + WS_H);
    float* camp   = (float*)(ws + WS_CAMP);

    prep_fused<<<4608 + 2352, 256, 0, stream>>>(x, Wb, A_bf, W_bf);
    conv_mfma<<<NSUB*13*16, 256, 0, stream>>>(A_bf, W_bf, bbp, out);
    cam_pool<<<NSUB*BATCH*8, 128, 0, stream>>>(out + OUT_FEAT, clsw, pooled, camp);
    mlp1_kernel<<<48 + 37, 256, 0, stream>>>(pooled, p1w, p1b, hbuf, camp, out + OUT_CAM);
    mlp2_kernel<<<NSUB, 256, 0, stream>>>(hbuf, p2w, p2b, out);
}

// Round 7
// 122.044 us; speedup vs baseline: 1.5719x; 1.0201x over previous
//
#include <hip/hip_runtime.h>
#include <hip/hip_bf16.h>
#include <math.h>

// Problem constants
#define NSUB   3
#define CFEAT  1024
#define KDIM   3072          // 3 * 32 * 32
#define MDIM   1568          // 32 * 49
#define BATCH  32
#define NMT    25            // M tiles of 64 (1600 rows, 2% pad)
#define NKT    96            // K tiles of 32

// Output layout (flat f32): ranking[32,3] | cam 3x2x[32,7,7] | feats 3x[32,1024,7,7]
#define OUT_CAM   96
#define OUT_FEAT  9504
#define FEAT_PER_BRANCH (BATCH * CFEAT * 49)   // 1605632

// Workspace byte offsets.
// A frags: 25*96*4 = 9600 chunks x 64 lanes x 16B = 9,830,400
// W frags: 48*96*4 = 18432 chunks x 64 lanes x 16B = 18,874,368
#define WS_A      0
#define WS_W      (9600 * 1024)
#define WS_POOLED (WS_W + 18432 * 1024)
#define WS_H      (WS_POOLED + NSUB * BATCH * CFEAT * 4)
#define WS_CAMP   (WS_H + NSUB * BATCH * 512 * 4)

typedef __attribute__((ext_vector_type(8))) short bf16x8;
typedef __attribute__((ext_vector_type(4))) float f32x4;

__device__ __forceinline__ short b16(float f){
    __hip_bfloat16 h = __float2bfloat16(f);
    return *reinterpret_cast<short*>(&h);
}
__device__ __forceinline__ bf16x8 pack8(float4 a, float4 b){
    bf16x8 r;
    r[0]=b16(a.x); r[1]=b16(a.y); r[2]=b16(a.z); r[3]=b16(a.w);
    r[4]=b16(b.x); r[5]=b16(b.y); r[6]=b16(b.z); r[7]=b16(b.w);
    return r;
}

// ---------------------------------------------------------------------------
// Prep into MFMA-fragment layout.
// Fragment (16x16x32 bf16 A/B operand): lane l holds rows (l&15), k = (l>>4)*8+j.
// Chunk index: A: (MT*96 + KT)*4 + mi ; W: (NTg*96 + KT)*4 + ni  (NTg = i*16+NT).
// Storage: frag[chunk][lane] of 16B -> wave reads 1KB contiguous per frag.
// Blocks 0..4607: W (18432 chunks). Blocks 4608..7007: A (9600 chunks).
// ---------------------------------------------------------------------------
__global__ __launch_bounds__(256) void prep_frag(
    const float* __restrict__ x, const float* __restrict__ w,
    bf16x8* __restrict__ Af, bf16x8* __restrict__ Wf)
{
    int bid = blockIdx.x, t = threadIdx.x;
    if (bid < 4608) {
        int g = bid * 256 + t;
        int chunk = g >> 6, l = g & 63;
        int ni = chunk & 3, KT = (chunk >> 2) % 96, NTg = chunk / 384;
        int n = NTg * 64 + ni * 16 + (l & 15);       // 0..3071 = flat (i,c)
        int k = KT * 32 + (l >> 4) * 8;
        const float* src = w + (size_t)n * KDIM + k;
        Wf[(size_t)chunk * 64 + l] = pack8(*(const float4*)src, *(const float4*)(src + 4));
    } else {
        int g = (bid - 4608) * 256 + t;
        int chunk = g >> 6, l = g & 63;
        int mi = chunk & 3, KT = (chunk >> 2) % 96, MT = chunk / 384;
        int m  = MT * 64 + mi * 16 + (l & 15);
        int k0 = KT * 32 + (l >> 4) * 8;
        bf16x8 v;
        if (m < MDIM) {
            int b = m / 49, p = m % 49, ph = p / 7, pw = p % 7;
            int ch = k0 >> 10, r = (k0 >> 5) & 31, s = k0 & 31;
            const float* src = x + (((size_t)(b*3 + ch)*224 + ph*32 + r)*224 + pw*32 + s);
            v = pack8(*(const float4*)src, *(const float4*)(src + 4));
        } else {
            v = (bf16x8){0,0,0,0,0,0,0,0};           // pad rows: zero (confined anyway)
        }
        Af[(size_t)chunk * 64 + l] = v;
    }
}

// ---------------------------------------------------------------------------
// Conv GEMM bf16 MFMA — NO LDS, NO BARRIERS. Wave tile 64x64 (4x4 16x16 frags),
// fragments streamed global->reg as coalesced 1KB dwordx4 lines from the
// frag-layout arrays (L1/L2-resident). Reg double-buffer, unroll-2 over k32.
// Block = 2 waves sharing the same A tile (wave w: NT = NTb + 8*w) -> A hits L1.
// Grid 3*25*8 = 600 = 8*75, bijective XCD swizzle, MT fastest (B panel L2-hot).
// ---------------------------------------------------------------------------
__global__ __launch_bounds__(128) void conv_mfma(
    const bf16x8* __restrict__ Af, const bf16x8* __restrict__ Wf,
    const float* __restrict__ bb, float* __restrict__ out)
{
    int bid = (int)blockIdx.x;
    bid = (bid & 7) * 75 + (bid >> 3);          // bijective XCD swizzle (600=8*75)
    const int i   = bid / 200;
    const int rem = bid % 200;
    const int NTb = rem / 25, MT = rem % 25;

    const int wv = threadIdx.x >> 6, l = threadIdx.x & 63;
    const int NT = NTb + wv * 8;
    const int lrow = l & 15, q = l >> 4;

    const bf16x8* Ab = Af + (size_t)(MT * 384) * 64 + l;          // + (KT*4+mi)*64
    const bf16x8* Bb = Wf + (size_t)((i*16 + NT) * 384) * 64 + l; // + (KT*4+ni)*64

    f32x4 acc[4][4] = {};
    bf16x8 fa0[4], fb0[4], fa1[4], fb1[4];

    // preload KT=0
#pragma unroll
    for (int m = 0; m < 4; ++m) { fa0[m] = Ab[m*64]; fb0[m] = Bb[m*64]; }

    for (int KT = 0; KT < NKT; KT += 2) {
        {   // prefetch KT+1 (always valid: NKT even)
            const bf16x8* An = Ab + (KT + 1) * 256;
            const bf16x8* Bn = Bb + (KT + 1) * 256;
#pragma unroll
            for (int m = 0; m < 4; ++m) { fa1[m] = An[m*64]; fb1[m] = Bn[m*64]; }
        }
#pragma unroll
        for (int mi = 0; mi < 4; ++mi)
#pragma unroll
            for (int ni = 0; ni < 4; ++ni)
                acc[mi][ni] = __builtin_amdgcn_mfma_f32_16x16x32_bf16(
                    fa0[mi], fb0[ni], acc[mi][ni], 0, 0, 0);
        if (KT + 2 < NKT) {   // prefetch KT+2
            const bf16x8* An = Ab + (KT + 2) * 256;
            const bf16x8* Bn = Bb + (KT + 2) * 256;
#pragma unroll
            for (int m = 0; m < 4; ++m) { fa0[m] = An[m*64]; fb0[m] = Bn[m*64]; }
        }
#pragma unroll
        for (int mi = 0; mi < 4; ++mi)
#pragma unroll
            for (int ni = 0; ni < 4; ++ni)
                acc[mi][ni] = __builtin_amdgcn_mfma_f32_16x16x32_bf16(
                    fa1[mi], fb1[ni], acc[mi][ni], 0, 0, 0);
    }

    // epilogue: bias + scatter to feats[i][b][c][p]
    float* featb = out + OUT_FEAT + (size_t)i * FEAT_PER_BRANCH;
    float bias[4];
#pragma unroll
    for (int ni = 0; ni < 4; ++ni)
        bias[ni] = bb[i*CFEAT + NT*64 + ni*16 + lrow];
#pragma unroll
    for (int mi = 0; mi < 4; ++mi) {
        int mbase = MT*64 + mi*16 + q*4;
#pragma unroll
        for (int rr = 0; rr < 4; ++rr) {
            int m = mbase + rr;
            if (m >= MDIM) continue;
            int b = m / 49, p = m % 49;
#pragma unroll
            for (int ni = 0; ni < 4; ++ni) {
                int n = NT*64 + ni*16 + lrow;
                featb[(size_t)(b*CFEAT + n)*49 + p] = acc[mi][ni][rr] + bias[ni];
            }
        }
    }
}

// ---------------------------------------------------------------------------
// Pool + partial CAM: 768 blocks (i, b, 128-channel chunk), 128 threads.
// ---------------------------------------------------------------------------
__global__ __launch_bounds__(128) void cam_pool(
    const float* __restrict__ feat, const float* __restrict__ cls_w,
    float* __restrict__ pooled, float* __restrict__ camp)
{
    __shared__ float fs[128][50];
    int bid = blockIdx.x;                  // (i*32+b)*8 + ch
    int i = bid >> 8, b = (bid >> 3) & 31, ch = bid & 7;
    int t = threadIdx.x;
    int c0 = ch * 128;
    const float* f = feat + ((size_t)(i*BATCH + b) * CFEAT + c0) * 49;

    for (int qq = 0; qq < 49; ++qq) {
        int e = qq*128 + t;
        fs[e / 49][e % 49] = f[e];
    }
    __syncthreads();

    {
        float s = 0.f;
#pragma unroll
        for (int k = 0; k < 49; ++k) s += fs[t][k];
        pooled[(size_t)(i*BATCH + b) * CFEAT + c0 + t] = s * (1.f/49.f);
    }

    if (t < 98) {
        int o = t / 49, p = t % 49;
        const float* w = cls_w + (size_t)i * 2 * CFEAT + o * CFEAT + c0;
        float s = 0.f;
        for (int c = 0; c < 128; ++c) s += w[c] * fs[c][p];
        camp[(size_t)bid * 98 + t] = s;
    }
}

// ---------------------------------------------------------------------------
// MLP layer 1 (blocks 0..47) + CAM finalize (blocks 48..84).
// ---------------------------------------------------------------------------
__global__ __launch_bounds__(256) void mlp1_kernel(
    const float* __restrict__ pooled, const float* __restrict__ p1w,
    const float* __restrict__ p1b, float* __restrict__ h,
    const float* __restrict__ camp, float* __restrict__ out_cam)
{
    if (blockIdx.x >= 48) {                 // CAM finalize: sum 8 chunk partials
        int fid = (blockIdx.x - 48) * 256 + threadIdx.x;
        if (fid < NSUB * 2 * MDIM) {
            int io = fid / MDIM, rem = fid % MDIM;
            int b = rem / 49, p = rem % 49;
            int i = io >> 1, o = io & 1;
            float s = 0.f;
#pragma unroll
            for (int c = 0; c < 8; ++c)
                s += camp[(size_t)(((i*BATCH + b)*8) + c) * 98 + o*49 + p];
            out_cam[fid] = fmaxf(s, 0.f);
        }
        return;
    }
    __shared__ float ps[32 * 256];
    int i = blockIdx.x >> 4, jc = blockIdx.x & 15;
    int t = threadIdx.x;
    int j = jc*32 + (t & 31);
    int bg = (t >> 5) * 4;
    float acc[4] = {};
    const float* wrow = p1w + ((size_t)i*512 + j) * CFEAT;
    for (int kc = 0; kc < 4; ++kc) {
        __syncthreads();
#pragma unroll
        for (int qq = 0; qq < 8; ++qq) {
            int f4 = t + qq*256;                 // 0..2047 float4s
            int b = f4 >> 6, k4 = (f4 & 63) * 4;
            *(float4*)&ps[b*256 + k4] =
                *(const float4*)&pooled[((size_t)i*32 + b)*CFEAT + kc*256 + k4];
        }
        __syncthreads();
        const float* wk = wrow + kc*256;
        for (int k = 0; k < 256; k += 4) {
            float4 w4 = *(const float4*)(wk + k);
#pragma unroll
            for (int qq = 0; qq < 4; ++qq) {
                const float* pr = &ps[(bg + qq)*256 + k];  // wave-uniform: broadcast
                acc[qq] += w4.x*pr[0] + w4.y*pr[1] + w4.z*pr[2] + w4.w*pr[3];
            }
        }
    }
    float bias = p1b[i*512 + j];
#pragma unroll
    for (int qq = 0; qq < 4; ++qq)
        h[((size_t)i*32 + bg + qq)*512 + j] = fmaxf(acc[qq] + bias, 0.f);
}

// ---------------------------------------------------------------------------
// MLP layer 2 + softmax[:,1]: block per branch.
// ---------------------------------------------------------------------------
__global__ void mlp2_kernel(const float* __restrict__ h, const float* __restrict__ p2w,
                            const float* __restrict__ p2b, float* __restrict__ out)
{
    __shared__ float part[256];
    int i = blockIdx.x, t = threadIdx.x;
    int b = t & 31, kc = t >> 5;                 // kc 0..7, 64 k each
    const float* hv = h + ((size_t)i*32 + b)*512 + kc*64;
    const float* w0 = p2w + (size_t)i*1024 + kc*64;
    const float* w1 = w0 + 512;
    float s = 0.f;
    for (int k = 0; k < 64; ++k) s += hv[k] * (w1[k] - w0[k]);
    part[t] = s;
    __syncthreads();
    if (t < 32) {
        float d = 0.f;
#pragma unroll
        for (int qq = 0; qq < 8; ++qq) d += part[qq*32 + t];
        d += p2b[i*2 + 1] - p2b[i*2 + 0];
        out[b*NSUB + i] = 1.f / (1.f + expf(-d));
    }
}

// ---------------------------------------------------------------------------
extern "C" void kernel_launch(void* const* d_in, const int* in_sizes, int n_in,
                              void* d_out, int out_size, void* d_ws, size_t ws_size,
                              hipStream_t stream)
{
    const float* x    = (const float*)d_in[0];
    const float* Wb   = (const float*)d_in[1];
    const float* bbp  = (const float*)d_in[2];
    const float* p1w  = (const float*)d_in[3];
    const float* p1b  = (const float*)d_in[4];
    const float* p2w  = (const float*)d_in[5];
    const float* p2b  = (const float*)d_in[6];
    const float* clsw = (const float*)d_in[7];
    float* out = (float*)d_out;

    char* ws = (char*)d_ws;
    bf16x8* Af    = (bf16x8*)(ws + WS_A);
    bf16x8* Wf    = (bf16x8*)(ws + WS_W);
    float* pooled = (float*)(ws + WS_POOLED);
    float* hbuf   = (float*)(ws + WS_H);
    float* camp   = (float*)(ws + WS_CAMP);

    prep_frag<<<4608 + 2400, 256, 0, stream>>>(x, Wb, Af, Wf);
    conv_mfma<<<600, 128, 0, stream>>>(Af, Wf, bbp, out);
    cam_pool<<<NSUB*BATCH*8, 128, 0, stream>>>(out + OUT_FEAT, clsw, pooled, camp);
    mlp1_kernel<<<48 + 37, 256, 0, stream>>>(pooled, p1w, p1b, hbuf, camp, out + OUT_CAM);
    mlp2_kernel<<<NSUB, 256, 0, stream>>>(hbuf, p2w, p2b, out);
}

// Round 8
// 109.621 us; speedup vs baseline: 1.7500x; 1.1133x over previous
//
#include <hip/hip_runtime.h>
#include <hip/hip_bf16.h>
#include <math.h>

// Problem constants
#define NSUB   3
#define CFEAT  1024
#define KDIM   3072          // 3 * 32 * 32
#define MDIM   1568          // 32 * 49
#define BATCH  32
#define NMT    25            // M tiles of 64 (1600 rows, 2% pad)
#define NKT    96            // K tiles of 32

// Output layout (flat f32): ranking[32,3] | cam 3x2x[32,7,7] | feats 3x[32,1024,7,7]
#define OUT_CAM   96
#define OUT_FEAT  9504
#define FEAT_PER_BRANCH (BATCH * CFEAT * 49)   // 1605632

// Workspace byte offsets.
// A frags: 25*96*4 = 9600 chunks x 64 lanes x 16B = 9,830,400
// W frags: 48*96*4 = 18432 chunks x 64 lanes x 16B = 18,874,368
#define WS_A      0
#define WS_W      (9600 * 1024)
#define WS_POOLED (WS_W + 18432 * 1024)
#define WS_H      (WS_POOLED + NSUB * BATCH * CFEAT * 4)
#define WS_CAMP   (WS_H + NSUB * BATCH * 512 * 4)

typedef __attribute__((ext_vector_type(8))) short bf16x8;
typedef __attribute__((ext_vector_type(4))) float f32x4;

__device__ __forceinline__ short b16(float f){
    __hip_bfloat16 h = __float2bfloat16(f);
    return *reinterpret_cast<short*>(&h);
}
__device__ __forceinline__ bf16x8 pack8(float4 a, float4 b){
    bf16x8 r;
    r[0]=b16(a.x); r[1]=b16(a.y); r[2]=b16(a.z); r[3]=b16(a.w);
    r[4]=b16(b.x); r[5]=b16(b.y); r[6]=b16(b.z); r[7]=b16(b.w);
    return r;
}

// ---------------------------------------------------------------------------
// Prep into MFMA-fragment layout.
// Fragment (16x16x32 bf16 A/B operand): lane l holds row (l&15), k = (l>>4)*8+j.
// Chunk index: A: (MT*96 + KT)*4 + mi ; W: (NTg*96 + KT)*4 + ni  (NTg = i*16+NT).
// Storage: frag[chunk][lane] of 16B -> wave reads 1KB contiguous per frag.
// ---------------------------------------------------------------------------
__global__ __launch_bounds__(256) void prep_frag(
    const float* __restrict__ x, const float* __restrict__ w,
    bf16x8* __restrict__ Af, bf16x8* __restrict__ Wf)
{
    int bid = blockIdx.x, t = threadIdx.x;
    if (bid < 4608) {
        int g = bid * 256 + t;
        int chunk = g >> 6, l = g & 63;
        int ni = chunk & 3, KT = (chunk >> 2) % 96, NTg = chunk / 384;
        int n = NTg * 64 + ni * 16 + (l & 15);       // 0..3071 = flat (i,c)
        int k = KT * 32 + (l >> 4) * 8;
        const float* src = w + (size_t)n * KDIM + k;
        Wf[(size_t)chunk * 64 + l] = pack8(*(const float4*)src, *(const float4*)(src + 4));
    } else {
        int g = (bid - 4608) * 256 + t;
        int chunk = g >> 6, l = g & 63;
        int mi = chunk & 3, KT = (chunk >> 2) % 96, MT = chunk / 384;
        int m  = MT * 64 + mi * 16 + (l & 15);
        int k0 = KT * 32 + (l >> 4) * 8;
        bf16x8 v;
        if (m < MDIM) {
            int b = m / 49, p = m % 49, ph = p / 7, pw = p % 7;
            int ch = k0 >> 10, r = (k0 >> 5) & 31, s = k0 & 31;
            const float* src = x + (((size_t)(b*3 + ch)*224 + ph*32 + r)*224 + pw*32 + s);
            v = pack8(*(const float4*)src, *(const float4*)(src + 4));
        } else {
            v = (bf16x8){0,0,0,0,0,0,0,0};           // pad rows: zero
        }
        Af[(size_t)chunk * 64 + l] = v;
    }
}

// ---------------------------------------------------------------------------
// Conv GEMM bf16 MFMA — no staging LDS, no barriers. Wave tile 64x64,
// fragments streamed global->reg as coalesced 1KB lines (L2/L3-resident).
// DEPTH-3 static register pipeline (a0/a1/a2): ~2 K-tiles of loads in flight
// covers L2/L3 latency (round-7 failure: depth-1 = 160cy cover vs ~400cy).
// Epilogue via per-wave LDS tile (pad 65) -> contiguous-p coalesced writes
// (kills RMW overfetch seen in round-7 FETCH/WRITE).
// Grid 3*25*8 = 600 = 8*75, bijective XCD swizzle, MT fastest.
// ---------------------------------------------------------------------------
__global__ __launch_bounds__(128, 2) void conv_mfma(
    const bf16x8* __restrict__ Af, const bf16x8* __restrict__ Wf,
    const float* __restrict__ bb, float* __restrict__ out)
{
    __shared__ float eplds[2][64 * 65];         // epilogue only

    int bid = (int)blockIdx.x;
    bid = (bid & 7) * 75 + (bid >> 3);          // bijective XCD swizzle (600=8*75)
    const int i   = bid / 200;
    const int rem = bid % 200;
    const int NTb = rem / 25, MT = rem % 25;

    const int wv = threadIdx.x >> 6, l = threadIdx.x & 63;
    const int NT = NTb + wv * 8;
    const int lrow = l & 15, q = l >> 4;

    const bf16x8* Ab = Af + (size_t)(MT * 384) * 64 + l;          // + (KT*4+mi)*64
    const bf16x8* Bb = Wf + (size_t)((i*16 + NT) * 384) * 64 + l; // + (KT*4+ni)*64

    f32x4 acc[4][4] = {};
    bf16x8 a0[4], b0[4], a1[4], b1[4], a2[4], b2[4];

    auto LOADT = [&](bf16x8 (&Ad)[4], bf16x8 (&Bd)[4], int KT){
        const bf16x8* An = Ab + KT * 256;
        const bf16x8* Bn = Bb + KT * 256;
#pragma unroll
        for (int m2 = 0; m2 < 4; ++m2) { Ad[m2] = An[m2*64]; Bd[m2] = Bn[m2*64]; }
    };
    auto MFMAT = [&](bf16x8 (&As)[4], bf16x8 (&Bs)[4]){
#pragma unroll
        for (int mi = 0; mi < 4; ++mi)
#pragma unroll
            for (int ni = 0; ni < 4; ++ni)
                acc[mi][ni] = __builtin_amdgcn_mfma_f32_16x16x32_bf16(
                    As[mi], Bs[ni], acc[mi][ni], 0, 0, 0);
    };

    LOADT(a0, b0, 0);
    LOADT(a1, b1, 1);
    for (int kt = 0; kt < NKT; kt += 3) {
        LOADT(a2, b2, kt + 2);
        MFMAT(a0, b0);
        if (kt + 3 < NKT) LOADT(a0, b0, kt + 3);
        MFMAT(a1, b1);
        if (kt + 4 < NKT) LOADT(a1, b1, kt + 4);
        MFMAT(a2, b2);
    }

    // ---- epilogue: acc -> per-wave LDS tile -> coalesced global writes ----
    float bias[4];
#pragma unroll
    for (int ni = 0; ni < 4; ++ni)
        bias[ni] = bb[i*CFEAT + NT*64 + ni*16 + lrow];
    float* ep = eplds[wv];
#pragma unroll
    for (int mi = 0; mi < 4; ++mi)
#pragma unroll
        for (int ni = 0; ni < 4; ++ni)
#pragma unroll
            for (int rr = 0; rr < 4; ++rr)
                ep[(mi*16 + q*4 + rr) * 65 + ni*16 + lrow] = acc[mi][ni][rr] + bias[ni];

    // same-wave LDS: no barrier needed (compiler orders via lgkmcnt)
    float* featb = out + OUT_FEAT + (size_t)i * FEAT_PER_BRANCH;
    int m = MT*64 + l;
    if (m < MDIM) {
        int b = m / 49, p = m % 49;
        float* base = featb + (size_t)(b*CFEAT + NT*64) * 49 + p;
#pragma unroll 8
        for (int c = 0; c < 64; ++c)
            base[c * 49] = ep[l*65 + c];
    }
}

// ---------------------------------------------------------------------------
// Pool + partial CAM: 768 blocks (i, b, 128-channel chunk), 128 threads.
// ---------------------------------------------------------------------------
__global__ __launch_bounds__(128) void cam_pool(
    const float* __restrict__ feat, const float* __restrict__ cls_w,
    float* __restrict__ pooled, float* __restrict__ camp)
{
    __shared__ float fs[128][50];
    int bid = blockIdx.x;                  // (i*32+b)*8 + ch
    int i = bid >> 8, b = (bid >> 3) & 31, ch = bid & 7;
    int t = threadIdx.x;
    int c0 = ch * 128;
    const float* f = feat + ((size_t)(i*BATCH + b) * CFEAT + c0) * 49;

    for (int qq = 0; qq < 49; ++qq) {
        int e = qq*128 + t;
        fs[e / 49][e % 49] = f[e];
    }
    __syncthreads();

    {
        float s = 0.f;
#pragma unroll
        for (int k = 0; k < 49; ++k) s += fs[t][k];
        pooled[(size_t)(i*BATCH + b) * CFEAT + c0 + t] = s * (1.f/49.f);
    }

    if (t < 98) {
        int o = t / 49, p = t % 49;
        const float* w = cls_w + (size_t)i * 2 * CFEAT + o * CFEAT + c0;
        float s = 0.f;
        for (int c = 0; c < 128; ++c) s += w[c] * fs[c][p];
        camp[(size_t)bid * 98 + t] = s;
    }
}

// ---------------------------------------------------------------------------
// MLP layer 1 (blocks 0..47) + CAM finalize (blocks 48..84).
// ---------------------------------------------------------------------------
__global__ __launch_bounds__(256) void mlp1_kernel(
    const float* __restrict__ pooled, const float* __restrict__ p1w,
    const float* __restrict__ p1b, float* __restrict__ h,
    const float* __restrict__ camp, float* __restrict__ out_cam)
{
    if (blockIdx.x >= 48) {                 // CAM finalize: sum 8 chunk partials
        int fid = (blockIdx.x - 48) * 256 + threadIdx.x;
        if (fid < NSUB * 2 * MDIM) {
            int io = fid / MDIM, rem = fid % MDIM;
            int b = rem / 49, p = rem % 49;
            int i = io >> 1, o = io & 1;
            float s = 0.f;
#pragma unroll
            for (int c = 0; c < 8; ++c)
                s += camp[(size_t)(((i*BATCH + b)*8) + c) * 98 + o*49 + p];
            out_cam[fid] = fmaxf(s, 0.f);
        }
        return;
    }
    __shared__ float ps[32 * 256];
    int i = blockIdx.x >> 4, jc = blockIdx.x & 15;
    int t = threadIdx.x;
    int j = jc*32 + (t & 31);
    int bg = (t >> 5) * 4;
    float acc[4] = {};
    const float* wrow = p1w + ((size_t)i*512 + j) * CFEAT;
    for (int kc = 0; kc < 4; ++kc) {
        __syncthreads();
#pragma unroll
        for (int qq = 0; qq < 8; ++qq) {
            int f4 = t + qq*256;                 // 0..2047 float4s
            int b = f4 >> 6, k4 = (f4 & 63) * 4;
            *(float4*)&ps[b*256 + k4] =
                *(const float4*)&pooled[((size_t)i*32 + b)*CFEAT + kc*256 + k4];
        }
        __syncthreads();
        const float* wk = wrow + kc*256;
        for (int k = 0; k < 256; k += 4) {
            float4 w4 = *(const float4*)(wk + k);
#pragma unroll
            for (int qq = 0; qq < 4; ++qq) {
                const float* pr = &ps[(bg + qq)*256 + k];  // wave-uniform: broadcast
                acc[qq] += w4.x*pr[0] + w4.y*pr[1] + w4.z*pr[2] + w4.w*pr[3];
            }
        }
    }
    float bias = p1b[i*512 + j];
#pragma unroll
    for (int qq = 0; qq < 4; ++qq)
        h[((size_t)i*32 + bg + qq)*512 + j] = fmaxf(acc[qq] + bias, 0.f);
}

// ---------------------------------------------------------------------------
// MLP layer 2 + softmax[:,1]: block per branch.
// ---------------------------------------------------------------------------
__global__ void mlp2_kernel(const float* __restrict__ h, const float* __restrict__ p2w,
                            const float* __restrict__ p2b, float* __restrict__ out)
{
    __shared__ float part[256];
    int i = blockIdx.x, t = threadIdx.x;
    int b = t & 31, kc = t >> 5;                 // kc 0..7, 64 k each
    const float* hv = h + ((size_t)i*32 + b)*512 + kc*64;
    const float* w0 = p2w + (size_t)i*1024 + kc*64;
    const float* w1 = w0 + 512;
    float s = 0.f;
    for (int k = 0; k < 64; ++k) s += hv[k] * (w1[k] - w0[k]);
    part[t] = s;
    __syncthreads();
    if (t < 32) {
        float d = 0.f;
#pragma unroll
        for (int qq = 0; qq < 8; ++qq) d += part[qq*32 + t];
        d += p2b[i*2 + 1] - p2b[i*2 + 0];
        out[b*NSUB + i] = 1.f / (1.f + expf(-d));
    }
}

// ---------------------------------------------------------------------------
extern "C" void kernel_launch(void* const* d_in, const int* in_sizes, int n_in,
                              void* d_out, int out_size, void* d_ws, size_t ws_size,
                              hipStream_t stream)
{
    const float* x    = (const float*)d_in[0];
    const float* Wb   = (const float*)d_in[1];
    const float* bbp  = (const float*)d_in[2];
    const float* p1w  = (const float*)d_in[3];
    const float* p1b  = (const float*)d_in[4];
    const float* p2w  = (const float*)d_in[5];
    const float* p2b  = (const float*)d_in[6];
    const float* clsw = (const float*)d_in[7];
    float* out = (float*)d_out;

    char* ws = (char*)d_ws;
    bf16x8* Af    = (bf16x8*)(ws + WS_A);
    bf16x8* Wf    = (bf16x8*)(ws + WS_W);
    float* pooled = (float*)(ws + WS_POOLED);
    float* hbuf   = (float*)(ws + WS_H);
    float* camp   = (float*)(ws + WS_CAMP);

    prep_frag<<<4608 + 2400, 256, 0, stream>>>(x, Wb, Af, Wf);
    conv_mfma<<<600, 128, 0, stream>>>(Af, Wf, bbp, out);
    cam_pool<<<NSUB*BATCH*8, 128, 0, stream>>>(out + OUT_FEAT, clsw, pooled, camp);
    mlp1_kernel<<<48 + 37, 256, 0, stream>>>(pooled, p1w, p1b, hbuf, camp, out + OUT_CAM);
    mlp2_kernel<<<NSUB, 256, 0, stream>>>(hbuf, p2w, p2b, out);
}

// Round 9
// 107.706 us; speedup vs baseline: 1.7812x; 1.0178x over previous
//
#include <hip/hip_runtime.h>
#include <hip/hip_bf16.h>
#include <math.h>

// Problem constants
#define NSUB   3
#define CFEAT  1024
#define KDIM   3072          // 3 * 32 * 32
#define MDIM   1568          // 32 * 49
#define BATCH  32
#define NMT    25            // M tiles of 64 (1600 rows, 2% pad)
#define NKT    96            // K tiles of 32

// Output layout (flat f32): ranking[32,3] | cam 3x2x[32,7,7] | feats 3x[32,1024,7,7]
#define OUT_CAM   96
#define OUT_FEAT  9504
#define FEAT_PER_BRANCH (BATCH * CFEAT * 49)   // 1605632

// Workspace byte offsets.
#define WS_A      0
#define WS_W      (9600 * 1024)
#define WS_POOLED (WS_W + 18432 * 1024)
#define WS_H      (WS_POOLED + NSUB * BATCH * CFEAT * 4)
#define WS_CAMP   (WS_H + NSUB * BATCH * 512 * 4)

typedef __attribute__((ext_vector_type(8))) short bf16x8;
typedef __attribute__((ext_vector_type(4))) float f32x4;

__device__ __forceinline__ short b16(float f){
    __hip_bfloat16 h = __float2bfloat16(f);
    return *reinterpret_cast<short*>(&h);
}
__device__ __forceinline__ bf16x8 pack8(float4 a, float4 b){
    bf16x8 r;
    r[0]=b16(a.x); r[1]=b16(a.y); r[2]=b16(a.z); r[3]=b16(a.w);
    r[4]=b16(b.x); r[5]=b16(b.y); r[6]=b16(b.z); r[7]=b16(b.w);
    return r;
}

// ---------------------------------------------------------------------------
// Prep into MFMA-fragment layout.
// Fragment (16x16x32 bf16 A/B operand): lane l holds row (l&15), k = (l>>4)*8+j.
// Chunk index: A: (MT*96 + KT)*4 + mi ; W: (NTg*96 + KT)*4 + ni  (NTg = i*16+NT).
// ---------------------------------------------------------------------------
__global__ __launch_bounds__(256) void prep_frag(
    const float* __restrict__ x, const float* __restrict__ w,
    bf16x8* __restrict__ Af, bf16x8* __restrict__ Wf)
{
    int bid = blockIdx.x, t = threadIdx.x;
    if (bid < 4608) {
        int g = bid * 256 + t;
        int chunk = g >> 6, l = g & 63;
        int ni = chunk & 3, KT = (chunk >> 2) % 96, NTg = chunk / 384;
        int n = NTg * 64 + ni * 16 + (l & 15);       // 0..3071 = flat (i,c)
        int k = KT * 32 + (l >> 4) * 8;
        const float* src = w + (size_t)n * KDIM + k;
        Wf[(size_t)chunk * 64 + l] = pack8(*(const float4*)src, *(const float4*)(src + 4));
    } else {
        int g = (bid - 4608) * 256 + t;
        int chunk = g >> 6, l = g & 63;
        int mi = chunk & 3, KT = (chunk >> 2) % 96, MT = chunk / 384;
        int m  = MT * 64 + mi * 16 + (l & 15);
        int k0 = KT * 32 + (l >> 4) * 8;
        bf16x8 v;
        if (m < MDIM) {
            int b = m / 49, p = m % 49, ph = p / 7, pw = p % 7;
            int ch = k0 >> 10, r = (k0 >> 5) & 31, s = k0 & 31;
            const float* src = x + (((size_t)(b*3 + ch)*224 + ph*32 + r)*224 + pw*32 + s);
            v = pack8(*(const float4*)src, *(const float4*)(src + 4));
        } else {
            v = (bf16x8){0,0,0,0,0,0,0,0};           // pad rows: zero
        }
        Af[(size_t)chunk * 64 + l] = v;
    }
}

// ---------------------------------------------------------------------------
// Conv GEMM bf16 MFMA — no staging LDS, no barriers. Wave tile 64x64,
// fragments streamed global->reg as coalesced 1KB lines (L2/L3-resident).
// DEPTH-4 register pipeline, PINNED with sched_barrier(0) fences so the
// compiler cannot collapse it (round-8 failure: VGPR=88 proved the pipeline
// was folded to depth-1; loads need ~250cy of cover).
// Epilogue via per-wave LDS tile (pad 65) -> contiguous coalesced writes.
// Grid 3*25*8 = 600 = 8*75, bijective XCD swizzle, MT fastest.
// ---------------------------------------------------------------------------
__global__ __launch_bounds__(128, 2) void conv_mfma(
    const bf16x8* __restrict__ Af, const bf16x8* __restrict__ Wf,
    const float* __restrict__ bb, float* __restrict__ out)
{
    __shared__ float eplds[2][64 * 65];         // epilogue only

    int bid = (int)blockIdx.x;
    bid = (bid & 7) * 75 + (bid >> 3);          // bijective XCD swizzle (600=8*75)
    const int i   = bid / 200;
    const int rem = bid % 200;
    const int NTb = rem / 25, MT = rem % 25;

    const int wv = threadIdx.x >> 6, l = threadIdx.x & 63;
    const int NT = NTb + wv * 8;
    const int lrow = l & 15, q = l >> 4;

    const bf16x8* Ab = Af + (size_t)(MT * 384) * 64 + l;          // + (KT*4+mi)*64
    const bf16x8* Bb = Wf + (size_t)((i*16 + NT) * 384) * 64 + l; // + (KT*4+ni)*64

    f32x4 acc[4][4] = {};
    bf16x8 a0[4], b0[4], a1[4], b1[4], a2[4], b2[4], a3[4], b3[4];

    auto LOADT = [&](bf16x8 (&Ad)[4], bf16x8 (&Bd)[4], int KT){
        const bf16x8* An = Ab + KT * 256;
        const bf16x8* Bn = Bb + KT * 256;
#pragma unroll
        for (int m2 = 0; m2 < 4; ++m2) { Ad[m2] = An[m2*64]; Bd[m2] = Bn[m2*64]; }
    };
    auto MFMAT = [&](bf16x8 (&As)[4], bf16x8 (&Bs)[4]){
        __builtin_amdgcn_s_setprio(1);
#pragma unroll
        for (int mi = 0; mi < 4; ++mi)
#pragma unroll
            for (int ni = 0; ni < 4; ++ni)
                acc[mi][ni] = __builtin_amdgcn_mfma_f32_16x16x32_bf16(
                    As[mi], Bs[ni], acc[mi][ni], 0, 0, 0);
        __builtin_amdgcn_s_setprio(0);
    };
#define SB() __builtin_amdgcn_sched_barrier(0)

    // prologue: fill depth-4 (32 loads in flight)
    LOADT(a0, b0, 0); LOADT(a1, b1, 1); LOADT(a2, b2, 2); LOADT(a3, b3, 3);
    SB();
    for (int kt = 0; kt < NKT; kt += 4) {
        MFMAT(a0, b0); SB();
        if (kt + 4 < NKT) { LOADT(a0, b0, kt + 4); } SB();
        MFMAT(a1, b1); SB();
        if (kt + 5 < NKT) { LOADT(a1, b1, kt + 5); } SB();
        MFMAT(a2, b2); SB();
        if (kt + 6 < NKT) { LOADT(a2, b2, kt + 6); } SB();
        MFMAT(a3, b3); SB();
        if (kt + 7 < NKT) { LOADT(a3, b3, kt + 7); } SB();
    }
#undef SB

    // ---- epilogue: acc -> per-wave LDS tile -> coalesced global writes ----
    float bias[4];
#pragma unroll
    for (int ni = 0; ni < 4; ++ni)
        bias[ni] = bb[i*CFEAT + NT*64 + ni*16 + lrow];
    float* ep = eplds[wv];
#pragma unroll
    for (int mi = 0; mi < 4; ++mi)
#pragma unroll
        for (int ni = 0; ni < 4; ++ni)
#pragma unroll
            for (int rr = 0; rr < 4; ++rr)
                ep[(mi*16 + q*4 + rr) * 65 + ni*16 + lrow] = acc[mi][ni][rr] + bias[ni];

    // same-wave LDS: compiler orders via lgkmcnt
    float* featb = out + OUT_FEAT + (size_t)i * FEAT_PER_BRANCH;
    int m = MT*64 + l;
    if (m < MDIM) {
        int b = m / 49, p = m % 49;
        float* base = featb + (size_t)(b*CFEAT + NT*64) * 49 + p;
#pragma unroll 8
        for (int c = 0; c < 64; ++c)
            base[c * 49] = ep[l*65 + c];
    }
}

// ---------------------------------------------------------------------------
// Pool + partial CAM: 768 blocks (i, b, 128-channel chunk), 128 threads.
// ---------------------------------------------------------------------------
__global__ __launch_bounds__(128) void cam_pool(
    const float* __restrict__ feat, const float* __restrict__ cls_w,
    float* __restrict__ pooled, float* __restrict__ camp)
{
    __shared__ float fs[128][50];
    int bid = blockIdx.x;                  // (i*32+b)*8 + ch
    int i = bid >> 8, b = (bid >> 3) & 31, ch = bid & 7;
    int t = threadIdx.x;
    int c0 = ch * 128;
    const float* f = feat + ((size_t)(i*BATCH + b) * CFEAT + c0) * 49;

    for (int qq = 0; qq < 49; ++qq) {
        int e = qq*128 + t;
        fs[e / 49][e % 49] = f[e];
    }
    __syncthreads();

    {
        float s = 0.f;
#pragma unroll
        for (int k = 0; k < 49; ++k) s += fs[t][k];
        pooled[(size_t)(i*BATCH + b) * CFEAT + c0 + t] = s * (1.f/49.f);
    }

    if (t < 98) {
        int o = t / 49, p = t % 49;
        const float* w = cls_w + (size_t)i * 2 * CFEAT + o * CFEAT + c0;
        float s = 0.f;
        for (int c = 0; c < 128; ++c) s += w[c] * fs[c][p];
        camp[(size_t)bid * 98 + t] = s;
    }
}

// ---------------------------------------------------------------------------
// MLP layer 1 (blocks 0..47) + CAM finalize (blocks 48..84).
// ---------------------------------------------------------------------------
__global__ __launch_bounds__(256) void mlp1_kernel(
    const float* __restrict__ pooled, const float* __restrict__ p1w,
    const float* __restrict__ p1b, float* __restrict__ h,
    const float* __restrict__ camp, float* __restrict__ out_cam)
{
    if (blockIdx.x >= 48) {                 // CAM finalize: sum 8 chunk partials
        int fid = (blockIdx.x - 48) * 256 + threadIdx.x;
        if (fid < NSUB * 2 * MDIM) {
            int io = fid / MDIM, rem = fid % MDIM;
            int b = rem / 49, p = rem % 49;
            int i = io >> 1, o = io & 1;
            float s = 0.f;
#pragma unroll
            for (int c = 0; c < 8; ++c)
                s += camp[(size_t)(((i*BATCH + b)*8) + c) * 98 + o*49 + p];
            out_cam[fid] = fmaxf(s, 0.f);
        }
        return;
    }
    __shared__ float ps[32 * 256];
    int i = blockIdx.x >> 4, jc = blockIdx.x & 15;
    int t = threadIdx.x;
    int j = jc*32 + (t & 31);
    int bg = (t >> 5) * 4;
    float acc[4] = {};
    const float* wrow = p1w + ((size_t)i*512 + j) * CFEAT;
    for (int kc = 0; kc < 4; ++kc) {
        __syncthreads();
#pragma unroll
        for (int qq = 0; qq < 8; ++qq) {
            int f4 = t + qq*256;                 // 0..2047 float4s
            int b = f4 >> 6, k4 = (f4 & 63) * 4;
            *(float4*)&ps[b*256 + k4] =
                *(const float4*)&pooled[((size_t)i*32 + b)*CFEAT + kc*256 + k4];
        }
        __syncthreads();
        const float* wk = wrow + kc*256;
        for (int k = 0; k < 256; k += 4) {
            float4 w4 = *(const float4*)(wk + k);
#pragma unroll
            for (int qq = 0; qq < 4; ++qq) {
                const float* pr = &ps[(bg + qq)*256 + k];  // wave-uniform: broadcast
                acc[qq] += w4.x*pr[0] + w4.y*pr[1] + w4.z*pr[2] + w4.w*pr[3];
            }
        }
    }
    float bias = p1b[i*512 + j];
#pragma unroll
    for (int qq = 0; qq < 4; ++qq)
        h[((size_t)i*32 + bg + qq)*512 + j] = fmaxf(acc[qq] + bias, 0.f);
}

// ---------------------------------------------------------------------------
// MLP layer 2 + softmax[:,1]: block per branch.
// ---------------------------------------------------------------------------
__global__ void mlp2_kernel(const float* __restrict__ h, const float* __restrict__ p2w,
                            const float* __restrict__ p2b, float* __restrict__ out)
{
    __shared__ float part[256];
    int i = blockIdx.x, t = threadIdx.x;
    int b = t & 31, kc = t >> 5;                 // kc 0..7, 64 k each
    const float* hv = h + ((size_t)i*32 + b)*512 + kc*64;
    const float* w0 = p2w + (size_t)i*1024 + kc*64;
    const float* w1 = w0 + 512;
    float s = 0.f;
    for (int k = 0; k < 64; ++k) s += hv[k] * (w1[k] - w0[k]);
    part[t] = s;
    __syncthreads();
    if (t < 32) {
        float d = 0.f;
#pragma unroll
        for (int qq = 0; qq < 8; ++qq) d += part[qq*32 + t];
        d += p2b[i*2 + 1] - p2b[i*2 + 0];
        out[b*NSUB + i] = 1.f / (1.f + expf(-d));
    }
}

// ---------------------------------------------------------------------------
extern "C" void kernel_launch(void* const* d_in, const int* in_sizes, int n_in,
                              void* d_out, int out_size, void* d_ws, size_t ws_size,
                              hipStream_t stream)
{
    const float* x    = (const float*)d_in[0];
    const float* Wb   = (const float*)d_in[1];
    const float* bbp  = (const float*)d_in[2];
    const float* p1w  = (const float*)d_in[3];
    const float* p1b  = (const float*)d_in[4];
    const float* p2w  = (const float*)d_in[5];
    const float* p2b  = (const float*)d_in[6];
    const float* clsw = (const float*)d_in[7];
    float* out = (float*)d_out;

    char* ws = (char*)d_ws;
    bf16x8* Af    = (bf16x8*)(ws + WS_A);
    bf16x8* Wf    = (bf16x8*)(ws + WS_W);
    float* pooled = (float*)(ws + WS_POOLED);
    float* hbuf   = (float*)(ws + WS_H);
    float* camp   = (float*)(ws + WS_CAMP);

    prep_frag<<<4608 + 2400, 256, 0, stream>>>(x, Wb, Af, Wf);
    conv_mfma<<<600, 128, 0, stream>>>(Af, Wf, bbp, out);
    cam_pool<<<NSUB*BATCH*8, 128, 0, stream>>>(out + OUT_FEAT, clsw, pooled, camp);
    mlp1_kernel<<<48 + 37, 256, 0, stream>>>(pooled, p1w, p1b, hbuf, camp, out + OUT_CAM);
    mlp2_kernel<<<NSUB, 256, 0, stream>>>(hbuf, p2w, p2b, out);
}